// Round 15
// baseline (142.263 us; speedup 1.0000x reference)
//
#include <hip/hip_runtime.h>

// GCN layer: support = X@W ; out = relu(scatter(vals * support[cols]) + bias)
// N_NODES=65536, N_EDGES=1048576, IN_F=OUT_F=64, fp32 in/out.
//
// Ledger: R2 CSR -> R5 bucket sort -> R7 MFMA bf16 GEMM + bf16 S -> R8 fused
// builds (144) -> R11 mega gemm+scatter (143) -> R12 fixed-cap buckets (118,
// BEST) -> R13 fp32-LDS-atomic wall (353us: ~180 Mops/s/CU, never hot-path)
// -> R14 per-row LDS bins NEUTRAL (121): gather phase-A bookkeeping was never
// the cost. R9's counters (FETCH 46MB, S16 random reads miss per-XCD L2)
// say the gather is LOAD-LATENCY bound at 8 outstanding/wave.
// R15: R12 base + gather phase B processes ROW PAIRS jointly: two independent
//      8-edge batches in flight (16 vmem outstanding/wave, 2x MLP). Per-row
//      accumulation order unchanged (absmax identical).

#define NF    64
#define NBKT  512      // dst-row buckets; 128 rows each (shift=7)
#define RPB   128      // rows per bucket
#define BCAP  3072     // fixed slots per bucket (mean 2048, +22 sigma)
#define CHUNK 4096     // edges per scatter chunk (256 thr x 16)

typedef __attribute__((ext_vector_type(8))) short bf16x8;
typedef __attribute__((ext_vector_type(4))) float floatx4;

__device__ __forceinline__ unsigned short f2bf(float f) {
    unsigned u = __float_as_uint(f);
    return (unsigned short)((u + 0x7FFFu + ((u >> 16) & 1u)) >> 16);   // RNE
}
__device__ __forceinline__ float bf2f(unsigned short h) {
    return __uint_as_float(((unsigned)h) << 16);
}

// ---------------------------------------------------------------------------
// Kernel 1 (MEGA): GEMM tiles and scatter chunks co-resident in one grid.
// 1280 blocks x 256 thr: b%5==4 -> scatter chunk b/5; else gemm tile.
// Scatter writes into FIXED bucket regions via global cursor reservation.
// ---------------------------------------------------------------------------
__global__ __launch_bounds__(256) void gemm_scatter(
    const float* __restrict__ X, const float* __restrict__ W,
    unsigned short* __restrict__ S16,
    const int* __restrict__ rows, const int* __restrict__ cols,
    const float* __restrict__ vals, int* __restrict__ bucket_cursor,
    int2* __restrict__ staged, int n_edges, int shift)
{
    __shared__ short xs[64 * 72];   // gemm: X tile [row][k] (2-way alias: free)
    __shared__ short wt[64 * 72];   // gemm: W^T    [n][k]
    __shared__ int   hist[NBKT];    // scatter
    __shared__ int   cur[NBKT];     // scatter (global write index per bucket)

    const int tid = threadIdx.x;
    const int b   = blockIdx.x;

    if (b % 5 != 4) {
        // ---------------- GEMM tile ----------------
        const int tile = (b / 5) * 4 + (b % 5);
        const int row0 = tile * 64;
        {
            const float4* W4 = (const float4*)W;
            #pragma unroll
            for (int it = 0; it < 4; ++it) {
                int idx = tid + 256 * it;
                int k = idx >> 4, n4 = idx & 15;
                float4 w = W4[idx];
                wt[(n4 * 4 + 0) * 72 + k] = f2bf(w.x);
                wt[(n4 * 4 + 1) * 72 + k] = f2bf(w.y);
                wt[(n4 * 4 + 2) * 72 + k] = f2bf(w.z);
                wt[(n4 * 4 + 3) * 72 + k] = f2bf(w.w);
            }
        }
        {
            const float4* X4 = (const float4*)X + (size_t)row0 * 16;
            #pragma unroll
            for (int it = 0; it < 4; ++it) {
                int idx = tid + 256 * it;
                int r = idx >> 4, c4 = idx & 15;
                float4 v = X4[idx];
                short4 s = { (short)f2bf(v.x), (short)f2bf(v.y),
                             (short)f2bf(v.z), (short)f2bf(v.w) };
                *(short4*)&xs[r * 72 + c4 * 4] = s;
            }
        }
        __syncthreads();

        const int w    = tid >> 6;
        const int lane = tid & 63;
        const int m    = lane & 15;
        const int q    = lane >> 4;

        const int a_off = (16 * w + m) * 72 + q * 8;
        const bf16x8 A0 = *(const bf16x8*)&xs[a_off];
        const bf16x8 A1 = *(const bf16x8*)&xs[a_off + 32];

        floatx4 acc[4];
        #pragma unroll
        for (int t = 0; t < 4; ++t) {
            const int b_off = (16 * t + m) * 72 + q * 8;
            const bf16x8 B0 = *(const bf16x8*)&wt[b_off];
            const bf16x8 B1 = *(const bf16x8*)&wt[b_off + 32];
            floatx4 c = {0.f, 0.f, 0.f, 0.f};
            c = __builtin_amdgcn_mfma_f32_16x16x32_bf16(A0, B0, c, 0, 0, 0);
            c = __builtin_amdgcn_mfma_f32_16x16x32_bf16(A1, B1, c, 0, 0, 0);
            acc[t] = c;
        }
        #pragma unroll
        for (int t = 0; t < 4; ++t)
            #pragma unroll
            for (int r = 0; r < 4; ++r)
                S16[(size_t)(row0 + 16 * w + q * 4 + r) * NF + 16 * t + m] =
                    f2bf(acc[t][r]);
    } else {
        // ---------------- scatter chunk ----------------
        const int chunk = b / 5;
        for (int i = tid; i < NBKT; i += 256) hist[i] = 0;
        __syncthreads();
        const int base = chunk * CHUNK;
        const int lim  = min(CHUNK, n_edges - base);

        if (lim == CHUNK) {
            const int4*   R4 = (const int4*)(rows + base);
            const int4*   C4 = (const int4*)(cols + base);
            const float4* V4 = (const float4*)(vals + base);
            int4 r0 = R4[tid], r1 = R4[tid + 256];
            int4 r2 = R4[tid + 512], r3 = R4[tid + 768];
            #define HINC(rr) atomicAdd(&hist[((unsigned)(rr)) >> shift], 1)
            HINC(r0.x); HINC(r0.y); HINC(r0.z); HINC(r0.w);
            HINC(r1.x); HINC(r1.y); HINC(r1.z); HINC(r1.w);
            HINC(r2.x); HINC(r2.y); HINC(r2.z); HINC(r2.w);
            HINC(r3.x); HINC(r3.y); HINC(r3.z); HINC(r3.w);
            #undef HINC
            __syncthreads();
            for (int i = tid; i < NBKT; i += 256) {
                int h = hist[i];
                cur[i] = h ? (i * BCAP + atomicAdd(&bucket_cursor[i], h)) : 0;
            }
            __syncthreads();
            int4 c0 = C4[tid], c1 = C4[tid + 256];
            int4 c2 = C4[tid + 512], c3 = C4[tid + 768];
            float4 v0 = V4[tid], v1 = V4[tid + 256];
            float4 v2 = V4[tid + 512], v3 = V4[tid + 768];
            #define PUT(rr, cc, vv) { \
                int bkt = ((unsigned)(rr)) >> shift; \
                int p = atomicAdd(&cur[bkt], 1); \
                if (p - bkt * BCAP < BCAP) \
                    staged[p] = make_int2((int)(((unsigned)(rr) << 16) | (unsigned)(cc)), \
                                          __float_as_int(vv)); }
            PUT(r0.x, c0.x, v0.x); PUT(r0.y, c0.y, v0.y);
            PUT(r0.z, c0.z, v0.z); PUT(r0.w, c0.w, v0.w);
            PUT(r1.x, c1.x, v1.x); PUT(r1.y, c1.y, v1.y);
            PUT(r1.z, c1.z, v1.z); PUT(r1.w, c1.w, v1.w);
            PUT(r2.x, c2.x, v2.x); PUT(r2.y, c2.y, v2.y);
            PUT(r2.z, c2.z, v2.z); PUT(r2.w, c2.w, v2.w);
            PUT(r3.x, c3.x, v3.x); PUT(r3.y, c3.y, v3.y);
            PUT(r3.z, c3.z, v3.z); PUT(r3.w, c3.w, v3.w);
            #undef PUT
        } else {
            for (int i = tid; i < lim; i += 256)
                atomicAdd(&hist[((unsigned)rows[base + i]) >> shift], 1);
            __syncthreads();
            for (int i = tid; i < NBKT; i += 256) {
                int h = hist[i];
                cur[i] = h ? (i * BCAP + atomicAdd(&bucket_cursor[i], h)) : 0;
            }
            __syncthreads();
            for (int i = tid; i < lim; i += 256) {
                int r = rows[base + i];
                int bkt = ((unsigned)r) >> shift;
                int p = atomicAdd(&cur[bkt], 1);
                if (p - bkt * BCAP < BCAP)
                    staged[p] = make_int2((int)(((unsigned)r << 16) | (unsigned)cols[base + i]),
                                          __float_as_int(vals[base + i]));
            }
        }
    }
}

// ---------------------------------------------------------------------------
// Kernel 2: one block (1024 thr, 16 waves) per bucket. Phase A: edges reg-
// cached (3/thread) -> LDS hist -> scan -> LDS-cursor sort into eds, storing
// (col<<6, val) for 32-bit phase-B addressing. Phase B: wave w owns rows
// 8w..8w+7 processed as 4 ROW PAIRS -- two independent 8-edge batches in
// flight (16 vmem outstanding, 2x R12's MLP); per-row order unchanged.
// ---------------------------------------------------------------------------
__global__ __launch_bounds__(1024) void bucket_gather(
    const int* __restrict__ bucket_cursor, const int2* __restrict__ staged,
    const unsigned short* __restrict__ S16, const float* __restrict__ bias,
    float* __restrict__ out)
{
    __shared__ int2 eds[BCAP];         // 24 KB
    __shared__ int  hist[RPB];
    __shared__ int  cur[RPB];
    __shared__ int  rstart[RPB + 1];

    const int k    = blockIdx.x;
    const int t    = threadIdx.x;
    const int cnt  = min(bucket_cursor[k], BCAP);
    const int base = k * BCAP;
    const int w    = t >> 6;
    const int lane = t & 63;

    // phase A: register-cached edges (3 per thread; 3072 = 3 x 1024)
    int2 eb[3];
    bool vld[3];
    #pragma unroll
    for (int p = 0; p < 3; ++p) {
        const int i = t + 1024 * p;
        vld[p] = (i < cnt);
        if (vld[p]) eb[p] = staged[base + i];
    }
    if (t < RPB) hist[t] = 0;
    __syncthreads();
    #pragma unroll
    for (int p = 0; p < 3; ++p)
        if (vld[p])
            atomicAdd(&hist[(((unsigned)eb[p].x) >> 16) & (RPB - 1)], 1);
    __syncthreads();
    const int v = (t < RPB) ? hist[t] : 0;
    for (int off = 1; off < RPB; off <<= 1) {
        int u = (t < RPB && t >= off) ? hist[t - off] : 0;
        __syncthreads();
        if (t < RPB) hist[t] += u;
        __syncthreads();
    }
    if (t < RPB) {
        rstart[t] = hist[t] - v;       // exclusive, bucket-relative
        cur[t]    = hist[t] - v;
    }
    if (t == 0) rstart[RPB] = cnt;
    __syncthreads();
    #pragma unroll
    for (int p = 0; p < 3; ++p)
        if (vld[p]) {
            int r = (((unsigned)eb[p].x) >> 16) & (RPB - 1);
            int pos = atomicAdd(&cur[r], 1);
            eds[pos] = make_int2((eb[p].x & 0xFFFF) << 6, eb[p].y);
        }
    __syncthreads();

    const float bv = bias[lane];

    // 8-edge batch into 8 accumulators (edges ej..ej+7 of array a[])
    #define BATCH8(A, J) { \
        const int4 q0 = *(const int4*)&eds[(J) + 0]; \
        const int4 q1 = *(const int4*)&eds[(J) + 2]; \
        const int4 q2 = *(const int4*)&eds[(J) + 4]; \
        const int4 q3 = *(const int4*)&eds[(J) + 6]; \
        A[0] += __int_as_float(q0.y) * bf2f(S16[(unsigned)(q0.x | lane)]); \
        A[1] += __int_as_float(q0.w) * bf2f(S16[(unsigned)(q0.z | lane)]); \
        A[2] += __int_as_float(q1.y) * bf2f(S16[(unsigned)(q1.x | lane)]); \
        A[3] += __int_as_float(q1.w) * bf2f(S16[(unsigned)(q1.z | lane)]); \
        A[4] += __int_as_float(q2.y) * bf2f(S16[(unsigned)(q2.x | lane)]); \
        A[5] += __int_as_float(q2.w) * bf2f(S16[(unsigned)(q2.z | lane)]); \
        A[6] += __int_as_float(q3.y) * bf2f(S16[(unsigned)(q3.x | lane)]); \
        A[7] += __int_as_float(q3.w) * bf2f(S16[(unsigned)(q3.z | lane)]); }
    #define EDGE1(A, J) { \
        const int2 e = eds[(J)]; \
        A[0] += __int_as_float(e.y) * bf2f(S16[(unsigned)(e.x | lane)]); }

    #pragma unroll
    for (int rp = 0; rp < 4; ++rp) {
        const int rowA = w * 8 + rp * 2;
        const int rowB = rowA + 1;
        int jA = rstart[rowA]; const int eA = rstart[rowA + 1];
        int jB = rstart[rowB]; const int eB = rstart[rowB + 1];

        float aA[8] = {0.f,0.f,0.f,0.f,0.f,0.f,0.f,0.f};
        float aB[8] = {0.f,0.f,0.f,0.f,0.f,0.f,0.f,0.f};

        // joint main loop: two independent 8-batches -> 16 loads in flight
        while (jA + 8 <= eA && jB + 8 <= eB) {
            BATCH8(aA, jA)
            BATCH8(aB, jB)
            jA += 8; jB += 8;
        }
        // drain A
        for (; jA + 8 <= eA; jA += 8) BATCH8(aA, jA)
        for (; jA < eA; ++jA)         EDGE1(aA, jA)
        // drain B
        for (; jB + 8 <= eB; jB += 8) BATCH8(aB, jB)
        for (; jB < eB; ++jB)         EDGE1(aB, jB)

        const float sA = bv + (((aA[0] + aA[1]) + (aA[2] + aA[3])) +
                               ((aA[4] + aA[5]) + (aA[6] + aA[7])));
        const float sB = bv + (((aB[0] + aB[1]) + (aB[2] + aB[3])) +
                               ((aB[4] + aB[5]) + (aB[6] + aB[7])));
        out[(size_t)(k * RPB + rowA) * NF + lane] = fmaxf(sA, 0.f);
        out[(size_t)(k * RPB + rowB) * NF + lane] = fmaxf(sB, 0.f);
    }
    #undef BATCH8
    #undef EDGE1
}

extern "C" void kernel_launch(void* const* d_in, const int* in_sizes, int n_in,
                              void* d_out, int out_size, void* d_ws, size_t ws_size,
                              hipStream_t stream)
{
    const float* X     = (const float*)d_in[0];
    const int*   erows = (const int*)  d_in[1];
    const int*   ecols = (const int*)  d_in[2];
    const float* evals = (const float*)d_in[3];
    const float* W     = (const float*)d_in[4];
    const float* bias  = (const float*)d_in[5];
    float*       out   = (float*)d_out;

    const int n_nodes = in_sizes[0] / NF;
    const int n_edges = in_sizes[1];
    int shift = 0; while ((NBKT << shift) < n_nodes) ++shift;   // 7

    // workspace layout
    char* ws = (char*)d_ws;
    unsigned short* S16 = (unsigned short*)(ws);                          // 8 MB
    int2* staged        = (int2*)(ws + (size_t)n_nodes * NF * 2);         // 12.6 MB
    int*  bucket_cursor = (int*)((char*)staged + (size_t)NBKT * BCAP * 8);// 2 KB

    const int gemm_tiles = n_nodes / 64;                 // 1024
    const int schunks    = (n_edges + CHUNK - 1) / CHUNK;// 256
    const int mega       = gemm_tiles + schunks;         // 1280 (4:1 interleave)

    hipMemsetAsync(bucket_cursor, 0, (size_t)NBKT * 4, stream);
    gemm_scatter<<<mega, 256, 0, stream>>>(X, W, S16, erows, ecols, evals,
                                           bucket_cursor, staged, n_edges, shift);
    bucket_gather<<<NBKT, 1024, 0, stream>>>(bucket_cursor, staged, S16, bias, out);
}

// Round 16
// 120.511 us; speedup vs baseline: 1.1805x; 1.1805x over previous
//
#include <hip/hip_runtime.h>

// GCN layer: support = X@W ; out = relu(scatter(vals * support[cols]) + bias)
// N_NODES=65536, N_EDGES=1048576, IN_F=OUT_F=64, fp32 in/out.
//
// Ledger: R2 CSR -> R5 bucket sort -> R7 MFMA bf16 GEMM + bf16 S -> R8 fused
// builds (144) -> R11 mega gemm+scatter (143) -> R12 fixed-cap buckets (118,
// BEST) -> R13 fp32-LDS-atomic wall (444; ~180 Mops/s/CU, never hot-path) ->
// R14 per-row LDS bins NEUTRAL (121) -> R15 row-pair dual-batch REGRESSED
// (142: 302K LDS conflicts + occupancy drop; MLP didn't double).
// R16: exact revert to R12 -- the measured optimum. Budget: ~48us harness ws
// re-poison fill (fixed) + ~28us mega + ~38us gather (random 128B S16 reads,
// 8MB working set vs 4MB/XCD L2 -> ~46MB HBM fetch; 7 variants failed to
// beat it) + ~4us overhead.

#define NF    64
#define NBKT  512      // dst-row buckets; 128 rows each (shift=7)
#define RPB   128      // rows per bucket
#define BCAP  3072     // fixed slots per bucket (mean 2048, +22 sigma)
#define CHUNK 4096     // edges per scatter chunk (256 thr x 16)

typedef __attribute__((ext_vector_type(8))) short bf16x8;
typedef __attribute__((ext_vector_type(4))) float floatx4;

__device__ __forceinline__ unsigned short f2bf(float f) {
    unsigned u = __float_as_uint(f);
    return (unsigned short)((u + 0x7FFFu + ((u >> 16) & 1u)) >> 16);   // RNE
}
__device__ __forceinline__ float bf2f(unsigned short h) {
    return __uint_as_float(((unsigned)h) << 16);
}

// ---------------------------------------------------------------------------
// Kernel 1 (MEGA): GEMM tiles and scatter chunks co-resident in one grid.
// 1280 blocks x 256 thr: b%5==4 -> scatter chunk b/5; else gemm tile.
// Scatter writes into FIXED bucket regions via global cursor reservation.
// ---------------------------------------------------------------------------
__global__ __launch_bounds__(256) void gemm_scatter(
    const float* __restrict__ X, const float* __restrict__ W,
    unsigned short* __restrict__ S16,
    const int* __restrict__ rows, const int* __restrict__ cols,
    const float* __restrict__ vals, int* __restrict__ bucket_cursor,
    int2* __restrict__ staged, int n_edges, int shift)
{
    __shared__ short xs[64 * 72];   // gemm: X tile [row][k] (2-way alias: free)
    __shared__ short wt[64 * 72];   // gemm: W^T    [n][k]
    __shared__ int   hist[NBKT];    // scatter
    __shared__ int   cur[NBKT];     // scatter (global write index per bucket)

    const int tid = threadIdx.x;
    const int b   = blockIdx.x;

    if (b % 5 != 4) {
        // ---------------- GEMM tile ----------------
        const int tile = (b / 5) * 4 + (b % 5);
        const int row0 = tile * 64;
        {
            const float4* W4 = (const float4*)W;
            #pragma unroll
            for (int it = 0; it < 4; ++it) {
                int idx = tid + 256 * it;
                int k = idx >> 4, n4 = idx & 15;
                float4 w = W4[idx];
                wt[(n4 * 4 + 0) * 72 + k] = f2bf(w.x);
                wt[(n4 * 4 + 1) * 72 + k] = f2bf(w.y);
                wt[(n4 * 4 + 2) * 72 + k] = f2bf(w.z);
                wt[(n4 * 4 + 3) * 72 + k] = f2bf(w.w);
            }
        }
        {
            const float4* X4 = (const float4*)X + (size_t)row0 * 16;
            #pragma unroll
            for (int it = 0; it < 4; ++it) {
                int idx = tid + 256 * it;
                int r = idx >> 4, c4 = idx & 15;
                float4 v = X4[idx];
                short4 s = { (short)f2bf(v.x), (short)f2bf(v.y),
                             (short)f2bf(v.z), (short)f2bf(v.w) };
                *(short4*)&xs[r * 72 + c4 * 4] = s;
            }
        }
        __syncthreads();

        const int w    = tid >> 6;
        const int lane = tid & 63;
        const int m    = lane & 15;
        const int q    = lane >> 4;

        const int a_off = (16 * w + m) * 72 + q * 8;
        const bf16x8 A0 = *(const bf16x8*)&xs[a_off];
        const bf16x8 A1 = *(const bf16x8*)&xs[a_off + 32];

        floatx4 acc[4];
        #pragma unroll
        for (int t = 0; t < 4; ++t) {
            const int b_off = (16 * t + m) * 72 + q * 8;
            const bf16x8 B0 = *(const bf16x8*)&wt[b_off];
            const bf16x8 B1 = *(const bf16x8*)&wt[b_off + 32];
            floatx4 c = {0.f, 0.f, 0.f, 0.f};
            c = __builtin_amdgcn_mfma_f32_16x16x32_bf16(A0, B0, c, 0, 0, 0);
            c = __builtin_amdgcn_mfma_f32_16x16x32_bf16(A1, B1, c, 0, 0, 0);
            acc[t] = c;
        }
        #pragma unroll
        for (int t = 0; t < 4; ++t)
            #pragma unroll
            for (int r = 0; r < 4; ++r)
                S16[(size_t)(row0 + 16 * w + q * 4 + r) * NF + 16 * t + m] =
                    f2bf(acc[t][r]);
    } else {
        // ---------------- scatter chunk ----------------
        const int chunk = b / 5;
        for (int i = tid; i < NBKT; i += 256) hist[i] = 0;
        __syncthreads();
        const int base = chunk * CHUNK;
        const int lim  = min(CHUNK, n_edges - base);

        if (lim == CHUNK) {
            const int4*   R4 = (const int4*)(rows + base);
            const int4*   C4 = (const int4*)(cols + base);
            const float4* V4 = (const float4*)(vals + base);
            int4 r0 = R4[tid], r1 = R4[tid + 256];
            int4 r2 = R4[tid + 512], r3 = R4[tid + 768];
            #define HINC(rr) atomicAdd(&hist[((unsigned)(rr)) >> shift], 1)
            HINC(r0.x); HINC(r0.y); HINC(r0.z); HINC(r0.w);
            HINC(r1.x); HINC(r1.y); HINC(r1.z); HINC(r1.w);
            HINC(r2.x); HINC(r2.y); HINC(r2.z); HINC(r2.w);
            HINC(r3.x); HINC(r3.y); HINC(r3.z); HINC(r3.w);
            #undef HINC
            __syncthreads();
            for (int i = tid; i < NBKT; i += 256) {
                int h = hist[i];
                cur[i] = h ? (i * BCAP + atomicAdd(&bucket_cursor[i], h)) : 0;
            }
            __syncthreads();
            int4 c0 = C4[tid], c1 = C4[tid + 256];
            int4 c2 = C4[tid + 512], c3 = C4[tid + 768];
            float4 v0 = V4[tid], v1 = V4[tid + 256];
            float4 v2 = V4[tid + 512], v3 = V4[tid + 768];
            #define PUT(rr, cc, vv) { \
                int bkt = ((unsigned)(rr)) >> shift; \
                int p = atomicAdd(&cur[bkt], 1); \
                if (p - bkt * BCAP < BCAP) \
                    staged[p] = make_int2((int)(((unsigned)(rr) << 16) | (unsigned)(cc)), \
                                          __float_as_int(vv)); }
            PUT(r0.x, c0.x, v0.x); PUT(r0.y, c0.y, v0.y);
            PUT(r0.z, c0.z, v0.z); PUT(r0.w, c0.w, v0.w);
            PUT(r1.x, c1.x, v1.x); PUT(r1.y, c1.y, v1.y);
            PUT(r1.z, c1.z, v1.z); PUT(r1.w, c1.w, v1.w);
            PUT(r2.x, c2.x, v2.x); PUT(r2.y, c2.y, v2.y);
            PUT(r2.z, c2.z, v2.z); PUT(r2.w, c2.w, v2.w);
            PUT(r3.x, c3.x, v3.x); PUT(r3.y, c3.y, v3.y);
            PUT(r3.z, c3.z, v3.z); PUT(r3.w, c3.w, v3.w);
            #undef PUT
        } else {
            for (int i = tid; i < lim; i += 256)
                atomicAdd(&hist[((unsigned)rows[base + i]) >> shift], 1);
            __syncthreads();
            for (int i = tid; i < NBKT; i += 256) {
                int h = hist[i];
                cur[i] = h ? (i * BCAP + atomicAdd(&bucket_cursor[i], h)) : 0;
            }
            __syncthreads();
            for (int i = tid; i < lim; i += 256) {
                int r = rows[base + i];
                int bkt = ((unsigned)r) >> shift;
                int p = atomicAdd(&cur[bkt], 1);
                if (p - bkt * BCAP < BCAP)
                    staged[p] = make_int2((int)(((unsigned)r << 16) | (unsigned)cols[base + i]),
                                          __float_as_int(vals[base + i]));
            }
        }
    }
}

// ---------------------------------------------------------------------------
// Kernel 2: one block (1024 thr, 16 waves) per bucket. Phase A: edges reg-
// cached (3/thread) -> LDS hist -> scan -> LDS-cursor sort into eds, storing
// (col<<6, val) so phase B addresses are 32-bit (S16[ex6|lane], saddr form).
// Phase B: wave w owns rows 8w..8w+7; full-wave gather (lane = feature,
// ushort load = 128 B/instr), x8 in flight; fused bias+ReLU.
// ---------------------------------------------------------------------------
__global__ __launch_bounds__(1024) void bucket_gather(
    const int* __restrict__ bucket_cursor, const int2* __restrict__ staged,
    const unsigned short* __restrict__ S16, const float* __restrict__ bias,
    float* __restrict__ out)
{
    __shared__ int2 eds[BCAP];         // 24 KB
    __shared__ int  hist[RPB];
    __shared__ int  cur[RPB];
    __shared__ int  rstart[RPB + 1];

    const int k    = blockIdx.x;
    const int t    = threadIdx.x;
    const int cnt  = min(bucket_cursor[k], BCAP);
    const int base = k * BCAP;
    const int w    = t >> 6;
    const int lane = t & 63;

    // phase A: register-cached edges (3 per thread; 3072 = 3 x 1024)
    int2 eb[3];
    bool vld[3];
    #pragma unroll
    for (int p = 0; p < 3; ++p) {
        const int i = t + 1024 * p;
        vld[p] = (i < cnt);
        if (vld[p]) eb[p] = staged[base + i];
    }
    if (t < RPB) hist[t] = 0;
    __syncthreads();
    #pragma unroll
    for (int p = 0; p < 3; ++p)
        if (vld[p])
            atomicAdd(&hist[(((unsigned)eb[p].x) >> 16) & (RPB - 1)], 1);
    __syncthreads();
    const int v = (t < RPB) ? hist[t] : 0;
    for (int off = 1; off < RPB; off <<= 1) {
        int u = (t < RPB && t >= off) ? hist[t - off] : 0;
        __syncthreads();
        if (t < RPB) hist[t] += u;
        __syncthreads();
    }
    if (t < RPB) {
        rstart[t] = hist[t] - v;       // exclusive, bucket-relative
        cur[t]    = hist[t] - v;
    }
    if (t == 0) rstart[RPB] = cnt;
    __syncthreads();
    #pragma unroll
    for (int p = 0; p < 3; ++p)
        if (vld[p]) {
            int r = (((unsigned)eb[p].x) >> 16) & (RPB - 1);
            int pos = atomicAdd(&cur[r], 1);
            // store ushort-index of the S row (col*64) + value
            eds[pos] = make_int2((eb[p].x & 0xFFFF) << 6, eb[p].y);
        }
    __syncthreads();

    const float bv = bias[lane];
    #pragma unroll
    for (int rr = 0; rr < 8; ++rr) {
        const int row = w * 8 + rr;
        const int jb = rstart[row];
        const int je = rstart[row + 1];
        float a0 = 0.f, a1 = 0.f, a2 = 0.f, a3 = 0.f;
        float a4 = 0.f, a5 = 0.f, a6 = 0.f, a7 = 0.f;
        int j = jb;
        for (; j + 8 <= je; j += 8) {
            const int2 e0 = eds[j + 0];
            const int2 e1 = eds[j + 1];
            const int2 e2 = eds[j + 2];
            const int2 e3 = eds[j + 3];
            const int2 e4 = eds[j + 4];
            const int2 e5 = eds[j + 5];
            const int2 e6 = eds[j + 6];
            const int2 e7 = eds[j + 7];
            a0 += __int_as_float(e0.y) * bf2f(S16[(unsigned)(e0.x | lane)]);
            a1 += __int_as_float(e1.y) * bf2f(S16[(unsigned)(e1.x | lane)]);
            a2 += __int_as_float(e2.y) * bf2f(S16[(unsigned)(e2.x | lane)]);
            a3 += __int_as_float(e3.y) * bf2f(S16[(unsigned)(e3.x | lane)]);
            a4 += __int_as_float(e4.y) * bf2f(S16[(unsigned)(e4.x | lane)]);
            a5 += __int_as_float(e5.y) * bf2f(S16[(unsigned)(e5.x | lane)]);
            a6 += __int_as_float(e6.y) * bf2f(S16[(unsigned)(e6.x | lane)]);
            a7 += __int_as_float(e7.y) * bf2f(S16[(unsigned)(e7.x | lane)]);
        }
        for (; j + 2 <= je; j += 2) {
            const int2 e0 = eds[j + 0];
            const int2 e1 = eds[j + 1];
            a0 += __int_as_float(e0.y) * bf2f(S16[(unsigned)(e0.x | lane)]);
            a1 += __int_as_float(e1.y) * bf2f(S16[(unsigned)(e1.x | lane)]);
        }
        if (j < je) {
            const int2 e = eds[j];
            a0 += __int_as_float(e.y) * bf2f(S16[(unsigned)(e.x | lane)]);
        }
        const float acc = bv +
            (((a0 + a1) + (a2 + a3)) + ((a4 + a5) + (a6 + a7)));
        out[(size_t)(k * RPB + row) * NF + lane] = fmaxf(acc, 0.f);
    }
}

extern "C" void kernel_launch(void* const* d_in, const int* in_sizes, int n_in,
                              void* d_out, int out_size, void* d_ws, size_t ws_size,
                              hipStream_t stream)
{
    const float* X     = (const float*)d_in[0];
    const int*   erows = (const int*)  d_in[1];
    const int*   ecols = (const int*)  d_in[2];
    const float* evals = (const float*)d_in[3];
    const float* W     = (const float*)d_in[4];
    const float* bias  = (const float*)d_in[5];
    float*       out   = (float*)d_out;

    const int n_nodes = in_sizes[0] / NF;
    const int n_edges = in_sizes[1];
    int shift = 0; while ((NBKT << shift) < n_nodes) ++shift;   // 7

    // workspace layout
    char* ws = (char*)d_ws;
    unsigned short* S16 = (unsigned short*)(ws);                          // 8 MB
    int2* staged        = (int2*)(ws + (size_t)n_nodes * NF * 2);         // 12.6 MB
    int*  bucket_cursor = (int*)((char*)staged + (size_t)NBKT * BCAP * 8);// 2 KB

    const int gemm_tiles = n_nodes / 64;                 // 1024
    const int schunks    = (n_edges + CHUNK - 1) / CHUNK;// 256
    const int mega       = gemm_tiles + schunks;         // 1280 (4:1 interleave)

    hipMemsetAsync(bucket_cursor, 0, (size_t)NBKT * 4, stream);
    gemm_scatter<<<mega, 256, 0, stream>>>(X, W, S16, erows, ecols, evals,
                                           bucket_cursor, staged, n_edges, shift);
    bucket_gather<<<NBKT, 1024, 0, stream>>>(bucket_cursor, staged, S16, bias, out);
}